// Round 7
// baseline (129.060 us; speedup 1.0000x reference)
//
#include <hip/hip_runtime.h>

// feature_seq (B=2, C=64, N=512) fp32. Window lengths [256, 1024, 512, 512].
// Output i is (B, N, C, L_i), concatenated flat in d_out.
// out[b][n][c][l] = (0 <= n - L/2 + l < N) ? in[b][c][n - L/2 + l] : 0
//
// R7: persistent blocks. R4-R6 showed the load path doesn't matter (118-126us
// for 3 different structures); theory is wave-lifetime overhead: 36864 tiny
// workgroups, each wave doing only 4 stores. Now 2304 blocks (9/CU), each
// looping over 16 contiguous 64KB tiles (1MB per block), same per-tile body:
// wave-uniform row -> buffer descriptor gather (HW bounds check zero-fills
// OOB lanes), __any(partial) scalar fallback for boundary straddles, nt
// stores.

constexpr int B = 2;
constexpr int C = 64;   // log2 = 6
constexpr int N = 512;  // log2 = 9

constexpr int SZ256  = B * N * C * 256;   // 16,777,216 floats
constexpr int SZ1024 = B * N * C * 1024;  // 67,108,864
constexpr int SZ512  = B * N * C * 512;   // 33,554,432

// 64KB tiles (1024 float4)
constexpr int TIL256  = SZ256  / 4 / 1024;  // 4096
constexpr int TIL1024 = SZ1024 / 4 / 1024;  // 16384
constexpr int TIL512  = SZ512  / 4 / 1024;  // 8192

constexpr int TPB = 16;                      // tiles per block
constexpr int NB256  = TIL256  / TPB;        // 256 blocks
constexpr int NB1024 = TIL1024 / TPB;        // 1024
constexpr int NB512  = TIL512  / TPB;        // 512
constexpr int NBLK = NB256 + NB1024 + 2 * NB512;  // 2304 (9 per CU)

typedef float f32x4 __attribute__((ext_vector_type(4)));

template <int L>
__device__ __forceinline__ void do_tile(const float* __restrict__ in,
                                        float* __restrict__ out,
                                        int tile, int tid) {
    constexpr int HALF = L / 2;
    constexpr int L4 = L / 4;
    constexpr int L4_BITS = (L == 256) ? 6 : (L == 512) ? 7 : 8;
    constexpr int KS = 256 >> L4_BITS;   // rest step per k

    f32x4* __restrict__ out4 = reinterpret_cast<f32x4*>(out);

    const int l4    = tid & (L4 - 1);
    const int lb    = l4 << 2;                // window-local element offset
    const int restT = tid >> L4_BITS;
    const int R0    = (tile * 1024) >> L4_BITS;

#pragma unroll
    for (int k = 0; k < 4; ++k) {
        int t    = tile * 1024 + k * 256 + tid;
        int rest = R0 + k * KS + restT;       // wave-uniform

        int c  = rest & (C - 1);
        int bb = rest >> 15;                  // rest / (N*C)
        int n  = (rest >> 6) & (N - 1);

        // wave-uniform row offset -> SGPR
        int roff = __builtin_amdgcn_readfirstlane((((bb << 6) | c) << 9));
        const float* __restrict__ row = in + roff;

        int idx = n - HALF + lb;              // per-lane window source index

        f32x4 v;
        bool partial = ((idx > -4) && (idx < 0)) || ((idx > N - 4) && (idx < N));
        if (__any(partial)) {
            v.x = ((unsigned)(idx)     < (unsigned)N) ? row[idx]     : 0.0f;
            v.y = ((unsigned)(idx + 1) < (unsigned)N) ? row[idx + 1] : 0.0f;
            v.z = ((unsigned)(idx + 2) < (unsigned)N) ? row[idx + 2] : 0.0f;
            v.w = ((unsigned)(idx + 3) < (unsigned)N) ? row[idx + 3] : 0.0f;
        } else {
            __amdgpu_buffer_rsrc_t srd = __builtin_amdgcn_make_buffer_rsrc(
                (void*)row, /*stride=*/(short)0,
                /*num_records=*/N * 4, /*flags=*/0x00020000);
            auto lv = __builtin_amdgcn_raw_buffer_load_b128(
                srd, (unsigned)(idx << 2), 0, 0);
            v = __builtin_bit_cast(f32x4, lv);
        }

        __builtin_nontemporal_store(v, out4 + t);
    }
}

template <int L>
__device__ __forceinline__ void do_seg(const float* __restrict__ in,
                                       float* __restrict__ out,
                                       int lblk, int tid) {
    // 16 contiguous 64KB tiles per block (1MB contiguous span)
#pragma unroll 1
    for (int i = 0; i < TPB; ++i) {
        do_tile<L>(in, out, lblk * TPB + i, tid);
    }
}

__global__ __launch_bounds__(256)
void msw_fused_kernel(const float* __restrict__ in, float* __restrict__ out) {
    const int blk = blockIdx.x;
    const int tid = threadIdx.x;

    if (blk < NB256) {
        do_seg<256>(in, out, blk, tid);
    } else if (blk < NB256 + NB1024) {
        do_seg<1024>(in, out + SZ256, blk - NB256, tid);
    } else if (blk < NB256 + NB1024 + NB512) {
        do_seg<512>(in, out + SZ256 + SZ1024, blk - (NB256 + NB1024), tid);
    } else {
        do_seg<512>(in, out + SZ256 + SZ1024 + SZ512,
                    blk - (NB256 + NB1024 + NB512), tid);
    }
}

extern "C" void kernel_launch(void* const* d_in, const int* in_sizes, int n_in,
                              void* d_out, int out_size, void* d_ws, size_t ws_size,
                              hipStream_t stream) {
    const float* in = (const float*)d_in[0];
    float* out = (float*)d_out;

    msw_fused_kernel<<<NBLK, 256, 0, stream>>>(in, out);
}

// Round 8
// 114.385 us; speedup vs baseline: 1.1283x; 1.1283x over previous
//
#include <hip/hip_runtime.h>

// feature_seq (B=2, C=64, N=512) fp32. Window lengths [256, 1024, 512, 512].
// Output i is (B, N, C, L_i), concatenated flat in d_out.
// out[b][n][c][l] = (0 <= n - L/2 + l < N) ? in[b][c][n - L/2 + l] : 0
//
// R8: branchless via padded input. R4-R7 showed load-path flavor and launch
// granularity don't move the needle; the unablated cost was the boundary
// scalar path, which covers ~37% of L=1024 waves (every window straddles
// both ends; partial float4s exist whenever n%4 != 0). Pre-kernel writes a
// zero-padded input copy to d_ws: per (b,c) row 1536 floats =
// [512 zeros | 512 data | 512 zeros] (768 KB, L2-resident). Main kernel then
// does ONE unconditional dword-aligned vector load per output float4 —
// no branches, no bounds checks, uniform waves.

constexpr int B = 2;
constexpr int C = 64;   // log2 = 6
constexpr int N = 512;  // log2 = 9

constexpr int SZ256  = B * N * C * 256;   // 16,777,216 floats
constexpr int SZ1024 = B * N * C * 1024;  // 67,108,864
constexpr int SZ512  = B * N * C * 512;   // 33,554,432

constexpr int BLK256  = SZ256  / 4 / 1024;  // 4096 blocks
constexpr int BLK1024 = SZ1024 / 4 / 1024;  // 16384
constexpr int BLK512  = SZ512  / 4 / 1024;  // 8192
constexpr int NBLK = BLK256 + BLK1024 + 2 * BLK512;  // 36864

constexpr int PROW = 1536;  // padded row length (floats): 512 zero | 512 | 512 zero

typedef float f32x4 __attribute__((ext_vector_type(4)));
typedef float f32x4u __attribute__((ext_vector_type(4), aligned(4)));

// 128 rows; 384 threads = one float4 slot each (slots 128..255 hold data).
__global__ __launch_bounds__(384)
void pad_kernel(const float* __restrict__ in, float* __restrict__ ws) {
    const int row = blockIdx.x;   // (b<<6)|c, 0..127
    const int p = threadIdx.x;    // float4 slot 0..383
    f32x4 v = {0.0f, 0.0f, 0.0f, 0.0f};
    if (p >= 128 && p < 256)
        v = *reinterpret_cast<const f32x4*>(in + (row << 9) + ((p - 128) << 2));
    *reinterpret_cast<f32x4*>(ws + row * PROW + (p << 2)) = v;
}

template <int L>
__device__ __forceinline__ void do_seg(const float* __restrict__ ws,
                                       float* __restrict__ out,
                                       int blk, int tid) {
    constexpr int HALF = L / 2;
    constexpr int BIAS = 512 - HALF;      // padded-row offset of window start @n=0
    constexpr int L4 = L / 4;
    constexpr int L4_BITS = (L == 256) ? 6 : (L == 512) ? 7 : 8;
    constexpr int KS = 256 >> L4_BITS;    // rest step per k

    f32x4* __restrict__ out4 = reinterpret_cast<f32x4*>(out);

    const int lb    = (tid & (L4 - 1)) << 2;   // window-local element offset
    const int restT = tid >> L4_BITS;
    const int R0    = (blk * 1024) >> L4_BITS;

#pragma unroll
    for (int k = 0; k < 4; ++k) {
        int t    = blk * 1024 + k * 256 + tid;
        int rest = R0 + k * KS + restT;        // wave-uniform

        int c  = rest & (C - 1);
        int bb = rest >> 15;                   // rest / (N*C)
        int n  = (rest >> 6) & (N - 1);
        int r  = (bb << 6) | c;                // padded row index

        // single unconditional load: padding guarantees in-bounds, zeros OOB
        const float* __restrict__ src = ws + r * PROW + BIAS + n + lb;
        f32x4 v = *reinterpret_cast<const f32x4u*>(src);

        __builtin_nontemporal_store(v, out4 + t);
    }
}

__global__ __launch_bounds__(256)
void msw_fused_kernel(const float* __restrict__ ws, float* __restrict__ out) {
    const int blk = blockIdx.x;
    const int tid = threadIdx.x;

    if (blk < BLK256) {
        do_seg<256>(ws, out, blk, tid);
    } else if (blk < BLK256 + BLK1024) {
        do_seg<1024>(ws, out + SZ256, blk - BLK256, tid);
    } else if (blk < BLK256 + BLK1024 + BLK512) {
        do_seg<512>(ws, out + SZ256 + SZ1024, blk - (BLK256 + BLK1024), tid);
    } else {
        do_seg<512>(ws, out + SZ256 + SZ1024 + SZ512,
                    blk - (BLK256 + BLK1024 + BLK512), tid);
    }
}

extern "C" void kernel_launch(void* const* d_in, const int* in_sizes, int n_in,
                              void* d_out, int out_size, void* d_ws, size_t ws_size,
                              hipStream_t stream) {
    const float* in = (const float*)d_in[0];
    float* out = (float*)d_out;
    float* ws = (float*)d_ws;   // needs B*C*PROW*4 = 786 KB scratch

    pad_kernel<<<B * C, 384, 0, stream>>>(in, ws);
    msw_fused_kernel<<<NBLK, 256, 0, stream>>>(ws, out);
}